// Round 5
// baseline (4429.924 us; speedup 1.0000x reference)
//
#include <hip/hip_runtime.h>
#include <cstdint>
#include <cstddef>
#include <cstring>

#define LSEQ 512
#define BATCH 64
#define DIM 256
#define HID 256
#define NTAG 11

// ---------------- init: zero group-barrier flags ----------------
__global__ void init_ctr(unsigned int* __restrict__ ctr) {
    for (int i = threadIdx.x; i < 1024; i += 256) ctr[i] = 0u;
}

// ---------------- input GEMM (+embedding gather, +bias) ----------------
// Gin layout: [dir][t_local][b>>2][n(1024)][b&3]
__global__ void __launch_bounds__(256) gemm_in(
    const int* __restrict__ sent, const float* __restrict__ emb,
    const float* __restrict__ Wf, const float* __restrict__ bf,
    const float* __restrict__ Wb, const float* __restrict__ bb,
    float* __restrict__ Gin, int t0, int CT)
{
    const int mt = blockIdx.x, nt = blockIdx.y, dir = blockIdx.z;
    const float* __restrict__ W    = dir ? Wb : Wf;
    const float* __restrict__ bias = dir ? bb : bf;
    const int tid = threadIdx.x;
    const int tx = tid & 15, ty = tid >> 4;

    __shared__ float As[128][36];
    __shared__ float Bs[128][36];

    const float* arow[4];
    const float* brow[4];
#pragma unroll
    for (int j = 0; j < 4; j++) {
        int v  = j * 256 + tid;
        int mi = v >> 3;
        int m_g = mt * 128 + mi;
        int b = m_g & 63, tl = m_g >> 6;
        int tg = t0 + tl;
        int tt = dir ? (LSEQ - 1 - tg) : tg;
        int tok = sent[b * LSEQ + tt];
        arow[j] = emb + (size_t)tok * DIM;
        brow[j] = W + (size_t)(nt * 128 + mi) * DIM;
    }

    float acc[8][8];
#pragma unroll
    for (int i = 0; i < 8; i++)
#pragma unroll
        for (int j = 0; j < 8; j++) acc[i][j] = 0.f;

    for (int ki = 0; ki < 8; ki++) {
        const int k0 = ki * 32;
        __syncthreads();
#pragma unroll
        for (int j = 0; j < 4; j++) {
            int v  = j * 256 + tid;
            int mi = v >> 3, k4 = v & 7;
            float4 av = *(const float4*)(arow[j] + k0 + k4 * 4);
            float4 bv = *(const float4*)(brow[j] + k0 + k4 * 4);
            *(float4*)&As[mi][k4 * 4] = av;
            *(float4*)&Bs[mi][k4 * 4] = bv;
        }
        __syncthreads();
#pragma unroll
        for (int k = 0; k < 32; k++) {
            float a[8], bv[8];
#pragma unroll
            for (int i = 0; i < 8; i++) a[i] = As[ty + 16 * i][k];
#pragma unroll
            for (int j = 0; j < 8; j++) bv[j] = Bs[tx + 16 * j][k];
#pragma unroll
            for (int i = 0; i < 8; i++)
#pragma unroll
                for (int j = 0; j < 8; j++) acc[i][j] = fmaf(a[i], bv[j], acc[i][j]);
        }
    }
#pragma unroll
    for (int i = 0; i < 8; i++) {
        int m_g = mt * 128 + ty + 16 * i;
        int b = m_g & 63, tl = m_g >> 6;
        size_t base = ((size_t)(dir * CT + tl) * 16 + (b >> 2)) * 4096 + (b & 3);
#pragma unroll
        for (int j = 0; j < 8; j++) {
            int n = nt * 128 + tx + 16 * j;
            Gin[base + (size_t)n * 4] = acc[i][j] + bias[n];
        }
    }
}

// ---------------- persistent bidirectional LSTM recurrence ----------------
// 256 WGs = 32 groups x 8 WGs (stride-32 members => same XCD heuristic).
// Group g: dir=g>>4, 4 batches bbase..bbase+3 split into TWO COHORTS
// {0,1} (A) and {2,3} (B), software-pipelined: while cohort A's stores/flags
// propagate through the MALL, the WG computes cohort B, and vice versa.
// Member w owns hidden j in [32w,32w+32) -> 128 W_hh rows in 128 VGPRs.
//
// Protocol (no fences, no RMW): producer stores h (agent atomics) ->
// __syncthreads (per-wave vmcnt(0) before s_barrier => stores acked at MALL)
// -> tid0 stores flag=t+1 (agent, relaxed). Consumer thread polls ONLY the
// flag of the WG that produced its slice (k8>>4), then loads that data —
// flag seen at MALL implies data acked at MALL. Ping-pong slot reuse is safe:
// flag[w']>=t implies w' consumed slot (t-2)&1 before writing step t-1.
__global__ void __launch_bounds__(256, 1) lstm_rec(
    const float* __restrict__ Gin,
    const float* __restrict__ Whh_f, const float* __restrict__ Whh_b,
    const float* __restrict__ h0, const float* __restrict__ c0,
    float* __restrict__ hs, float* __restrict__ hbuf, float* __restrict__ cbuf,
    unsigned int* __restrict__ ctr, int t0, int CT)
{
    const int wg = blockIdx.x;
    const int w = wg >> 5, g = wg & 31;
    const int dir   = g >> 4;
    const int bbase = (g & 15) << 2;
    const int jbase = w << 5;
    const int tid = threadIdx.x;
    const int r = tid & 127, s = tid >> 7;          // row 0..127, k-half
    const int q = r >> 5, jj = r & 31;
    const int row_g = (q << 8) + jbase + jj;        // gate-row in [0,1024)
    const float* __restrict__ Whh = dir ? Whh_b : Whh_f;

    float4 wreg[32];
    {
        const float4* wp = (const float4*)(Whh + (size_t)row_g * HID + s * 128);
#pragma unroll
        for (int i = 0; i < 32; i++) wreg[i] = wp[i];
    }

    __shared__ float4 HlA[2][64];        // staged h, cohort A (2 batches)
    __shared__ float4 HlB[2][64];        // staged h, cohort B
    __shared__ float  part_f[128][5];    // [row][s*2+c], stride 5 (2-way max = free)
    __shared__ float  gsum_f[4 * 66];    // [gate][c*33+jj], conflict-free

    const int b2c = tid >> 5, jj2 = tid & 31;       // act-phase ownership (tid<64)
    float cA = 0.f, cB = 0.f;
    if (tid < 64) {
        size_t ci = ((size_t)(dir * BATCH) + bbase + b2c) * HID + jbase + jj2;
        const float* csrc = (t0 == 0) ? c0 : cbuf;
        cA = csrc[ci];
        cB = csrc[ci + 2 * HID];
    }

    const int bsel = tid >> 7, k8 = tid & 127;      // staging: batch-in-cohort, 8B slot
    unsigned int* flagsA = ctr + g * 32;            // [w]
    unsigned int* flagsB = ctr + g * 32 + 16;       // [w]
    const unsigned int* myflagA = flagsA + (k8 >> 4);  // producer of my slice
    const unsigned int* myflagB = flagsB + (k8 >> 4);

    const size_t gin_wg_base = (size_t)(dir * CT) * 16384 + (size_t)(bbase >> 2) * 1024;
    const float4* __restrict__ Gin4 = (const float4*)Gin;

    // prefetch Gin for first step (all 4 batches: .xy = cohort A, .zw = B)
    float4 gv = make_float4(0.f, 0.f, 0.f, 0.f);
    if (tid < 128)
        gv = Gin4[gin_wg_base + row_g];

    for (int t = t0; t < t0 + CT; t++) {
        const int rp = (t - 1) & 1, wp2 = t & 1;
        const float* hb_r = hbuf + ((size_t)rp * 2 + dir) * BATCH * HID;
        float* hb_w = hbuf + ((size_t)wp2 * 2 + dir) * BATCH * HID;
        const int t_orig = dir ? (LSEQ - 1 - t) : t;

        // ================= phase A: batches bbase+0, bbase+1 =================
        {
            if (t > 0) {
                const unsigned int tgt = (unsigned int)t;
                while (__hip_atomic_load(myflagA, __ATOMIC_RELAXED,
                                         __HIP_MEMORY_SCOPE_AGENT) < tgt)
                    __builtin_amdgcn_s_sleep(1);
            }
            const float* hp = ((t == 0) ? (h0 + (size_t)dir * BATCH * HID)
                                        : hb_r)
                              + (size_t)(bbase + bsel) * HID + k8 * 2;
            unsigned long long u = __hip_atomic_load(
                (const unsigned long long*)hp, __ATOMIC_RELAXED,
                __HIP_MEMORY_SCOPE_AGENT);
            float2 hvv; memcpy(&hvv, &u, 8);
            ((float2*)HlA)[bsel * 128 + k8] = hvv;
        }
        // prefetch Gin for t+1 (consumed next iter; hidden behind both GEMVs)
        float4 gvn = make_float4(0.f, 0.f, 0.f, 0.f);
        {
            int tln = (t + 1 < t0 + CT) ? (t + 1 - t0) : (CT - 1);
            if (tid < 128)
                gvn = Gin4[gin_wg_base + (size_t)tln * 16384 + row_g];
        }
        __syncthreads();

        float ax = 0.f, ay = 0.f;
#pragma unroll
        for (int i = 0; i < 32; i++) {
            const int k4 = (s << 5) + i;
            const float4 wv = wreg[i];
            float4 hv;
            hv = HlA[0][k4];
            ax = fmaf(wv.x, hv.x, ax); ax = fmaf(wv.y, hv.y, ax);
            ax = fmaf(wv.z, hv.z, ax); ax = fmaf(wv.w, hv.w, ax);
            hv = HlA[1][k4];
            ay = fmaf(wv.x, hv.x, ay); ay = fmaf(wv.y, hv.y, ay);
            ay = fmaf(wv.z, hv.z, ay); ay = fmaf(wv.w, hv.w, ay);
        }
        part_f[r][s * 2 + 0] = ax;
        part_f[r][s * 2 + 1] = ay;
        __syncthreads();

        if (tid < 128) {
            float t0s = part_f[tid][0] + part_f[tid][2] + gv.x;
            float t1s = part_f[tid][1] + part_f[tid][3] + gv.y;
            gsum_f[q * 66 + jj] = t0s;
            gsum_f[q * 66 + 33 + jj] = t1s;
        }
        __syncthreads();

        if (tid < 64) {
            const int o = b2c * 33 + jj2;
            const float gi_ = gsum_f[0 * 66 + o];
            const float gf_ = gsum_f[1 * 66 + o];
            const float gg_ = gsum_f[2 * 66 + o];
            const float go_ = gsum_f[3 * 66 + o];
            const float ig = 1.f / (1.f + expf(-gi_));
            const float fg = 1.f / (1.f + expf(-gf_));
            const float og = 1.f / (1.f + expf(-go_));
            cA = fg * cA + ig * tanhf(gg_);
            const float hv = og * tanhf(cA);
            hs[((size_t)(dir * LSEQ + t_orig) * BATCH + bbase + b2c) * HID + jbase + jj2] = hv;
            __hip_atomic_store(
                &hb_w[(size_t)(bbase + b2c) * HID + jbase + jj2],
                hv, __ATOMIC_RELAXED, __HIP_MEMORY_SCOPE_AGENT);
        }
        __syncthreads();   // all waves vmcnt(0) before barrier => h acked at MALL
        if (tid == 0)
            __hip_atomic_store(&flagsA[w], (unsigned int)(t + 1),
                               __ATOMIC_RELAXED, __HIP_MEMORY_SCOPE_AGENT);

        // ================= phase B: batches bbase+2, bbase+3 =================
        {
            if (t > 0) {
                const unsigned int tgt = (unsigned int)t;
                while (__hip_atomic_load(myflagB, __ATOMIC_RELAXED,
                                         __HIP_MEMORY_SCOPE_AGENT) < tgt)
                    __builtin_amdgcn_s_sleep(1);
            }
            const float* hp = ((t == 0) ? (h0 + (size_t)dir * BATCH * HID)
                                        : hb_r)
                              + (size_t)(bbase + 2 + bsel) * HID + k8 * 2;
            unsigned long long u = __hip_atomic_load(
                (const unsigned long long*)hp, __ATOMIC_RELAXED,
                __HIP_MEMORY_SCOPE_AGENT);
            float2 hvv; memcpy(&hvv, &u, 8);
            ((float2*)HlB)[bsel * 128 + k8] = hvv;
        }
        __syncthreads();

        float bx = 0.f, by = 0.f;
#pragma unroll
        for (int i = 0; i < 32; i++) {
            const int k4 = (s << 5) + i;
            const float4 wv = wreg[i];
            float4 hv;
            hv = HlB[0][k4];
            bx = fmaf(wv.x, hv.x, bx); bx = fmaf(wv.y, hv.y, bx);
            bx = fmaf(wv.z, hv.z, bx); bx = fmaf(wv.w, hv.w, bx);
            hv = HlB[1][k4];
            by = fmaf(wv.x, hv.x, by); by = fmaf(wv.y, hv.y, by);
            by = fmaf(wv.z, hv.z, by); by = fmaf(wv.w, hv.w, by);
        }
        part_f[r][s * 2 + 0] = bx;
        part_f[r][s * 2 + 1] = by;
        __syncthreads();

        if (tid < 128) {
            float t0s = part_f[tid][0] + part_f[tid][2] + gv.z;
            float t1s = part_f[tid][1] + part_f[tid][3] + gv.w;
            gsum_f[q * 66 + jj] = t0s;
            gsum_f[q * 66 + 33 + jj] = t1s;
        }
        __syncthreads();

        if (tid < 64) {
            const int o = b2c * 33 + jj2;
            const float gi_ = gsum_f[0 * 66 + o];
            const float gf_ = gsum_f[1 * 66 + o];
            const float gg_ = gsum_f[2 * 66 + o];
            const float go_ = gsum_f[3 * 66 + o];
            const float ig = 1.f / (1.f + expf(-gi_));
            const float fg = 1.f / (1.f + expf(-gf_));
            const float og = 1.f / (1.f + expf(-go_));
            cB = fg * cB + ig * tanhf(gg_);
            const float hv = og * tanhf(cB);
            hs[((size_t)(dir * LSEQ + t_orig) * BATCH + bbase + 2 + b2c) * HID + jbase + jj2] = hv;
            __hip_atomic_store(
                &hb_w[(size_t)(bbase + 2 + b2c) * HID + jbase + jj2],
                hv, __ATOMIC_RELAXED, __HIP_MEMORY_SCOPE_AGENT);
        }
        __syncthreads();
        if (tid == 0)
            __hip_atomic_store(&flagsB[w], (unsigned int)(t + 1),
                               __ATOMIC_RELAXED, __HIP_MEMORY_SCOPE_AGENT);
        gv = gvn;
    }
    if (tid < 64) {
        size_t ci = ((size_t)(dir * BATCH) + bbase + b2c) * HID + jbase + jj2;
        cbuf[ci] = cA;
        cbuf[ci + 2 * HID] = cB;
    }
}

// ---------------- output projection: logits[b][t][11] ----------------
__global__ void __launch_bounds__(256) logits_k(
    const float* __restrict__ hs, const float* __restrict__ Wout,
    const float* __restrict__ bout, float* __restrict__ logits)
{
    const int tid = threadIdx.x;
    const int rt = tid >> 4, tg = tid & 15;
    __shared__ float hrow[16][516];
    __shared__ float Wl[NTAG][516];
    const int rbase = blockIdx.x * 16;

#pragma unroll
    for (int i = 0; i < 8; i++) {
        int u  = tid + i * 256;
        int rr = u >> 7, c4 = u & 127;
        int r_g = rbase + rr;
        int b = r_g >> 9, t = r_g & 511;
        int d = (c4 >= 64) ? 1 : 0, k4 = c4 & 63;
        float4 hv = ((const float4*)hs)[(((size_t)d * LSEQ + t) * BATCH + b) * 64 + k4];
        *(float4*)&hrow[rr][c4 * 4] = hv;
    }
    for (int u = tid; u < NTAG * 128; u += 256) {
        int row = u >> 7, c4 = u & 127;
        float4 wv = ((const float4*)Wout)[(size_t)row * 128 + c4];
        *(float4*)&Wl[row][c4 * 4] = wv;
    }
    __syncthreads();

    if (tg < NTAG) {
        const float4* hp = (const float4*)&hrow[rt][0];
        const float4* wp = (const float4*)&Wl[tg][0];
        float acc = 0.f;
#pragma unroll 4
        for (int k = 0; k < 128; k++) {
            float4 h = hp[k], ww = wp[k];
            acc = fmaf(h.x, ww.x, acc); acc = fmaf(h.y, ww.y, acc);
            acc = fmaf(h.z, ww.z, acc); acc = fmaf(h.w, ww.w, acc);
        }
        int r_g = rbase + rt;
        logits[(size_t)r_g * NTAG + tg] = acc + bout[tg];
    }
}

// ---------------- Viterbi (one wave per batch element) ----------------
__global__ void __launch_bounds__(64) viterbi_k(
    const float* __restrict__ logits, const float* __restrict__ trans,
    float* __restrict__ out)
{
    const int b = blockIdx.x, lane = threadIdx.x;
    __shared__ float lgl[LSEQ * NTAG];
    __shared__ unsigned char bp[LSEQ][16];
    __shared__ float pathf[LSEQ];

    {
        const float4* src = (const float4*)(logits + (size_t)b * LSEQ * NTAG);
        float4* dst = (float4*)lgl;
        for (int u = lane; u < (LSEQ * NTAG) / 4; u += 64) dst[u] = src[u];
    }
    float tcol[NTAG];
    if (lane < NTAG) {
#pragma unroll
        for (int i = 0; i < NTAG; i++) tcol[i] = trans[i * NTAG + lane];
    }
    __syncthreads();

    float v = (lane < NTAG) ? lgl[lane] : -1e30f;
    for (int t = 1; t < LSEQ; t++) {
        float best = -1e30f; int bi = 0;
#pragma unroll
        for (int i = 0; i < NTAG; i++) {
            float vi = __shfl(v, i, 64) + tcol[i];
            if (vi > best) { best = vi; bi = i; }   // strict > == first-max
        }
        if (lane < NTAG) {
            v = lgl[t * NTAG + lane] + best;
            bp[t][lane] = (unsigned char)bi;
        }
    }
    float bestv = -1e30f; int bestj = 0;
#pragma unroll
    for (int j = 0; j < NTAG; j++) {
        float vj = __shfl(v, j, 64);
        if (vj > bestv) { bestv = vj; bestj = j; }
    }
    if (lane == 0) {
        out[b] = bestv;
        int st = bestj;
        pathf[LSEQ - 1] = (float)st;
        for (int t = LSEQ - 1; t >= 1; t--) { st = bp[t][st]; pathf[t - 1] = (float)st; }
    }
    __syncthreads();
    for (int t = lane; t < LSEQ; t += 64)
        out[BATCH + (size_t)b * LSEQ + t] = pathf[t];
}

// ---------------- host ----------------
extern "C" void kernel_launch(void* const* d_in, const int* in_sizes, int n_in,
                              void* d_out, int out_size, void* d_ws, size_t ws_size,
                              hipStream_t stream)
{
    (void)in_sizes; (void)n_in; (void)out_size;
    const int*   sent  = (const int*)  d_in[0];
    const float* emb   = (const float*)d_in[1];
    const float* Wihf  = (const float*)d_in[2];
    const float* Whhf  = (const float*)d_in[3];
    const float* bf    = (const float*)d_in[4];
    const float* Wihb  = (const float*)d_in[5];
    const float* Whhb  = (const float*)d_in[6];
    const float* bb    = (const float*)d_in[7];
    const float* Wout  = (const float*)d_in[8];
    const float* bout  = (const float*)d_in[9];
    const float* trans = (const float*)d_in[10];
    const float* h0    = (const float*)d_in[11];
    const float* c0    = (const float*)d_in[12];
    float* out = (float*)d_out;

    const size_t fixed = 16777216ull + 65536ull + 32768ull + 360448ull + 1024ull;
    int CT = LSEQ;
    while (CT > 8 && ((size_t)CT * 131072ull + fixed) * 4ull > ws_size) CT >>= 1;

    float* ws = (float*)d_ws;
    size_t off = 0;
    float* Gin  = ws + off; off += (size_t)CT * 131072ull;
    float* hs   = ws + off; off += 16777216ull;
    float* hbuf = ws + off; off += 65536ull;
    float* cbuf = ws + off; off += 32768ull;
    float* lgts = ws + off; off += 360448ull;
    unsigned int* ctr = (unsigned int*)(ws + off);

    hipLaunchKernelGGL(init_ctr, dim3(1), dim3(256), 0, stream, ctr);

    const int nch = LSEQ / CT;
    for (int c = 0; c < nch; c++) {
        int t0 = c * CT;
        hipLaunchKernelGGL(gemm_in, dim3(CT / 2, 8, 2), dim3(256), 0, stream,
                           sent, emb, Wihf, bf, Wihb, bb, Gin, t0, CT);
        hipLaunchKernelGGL(lstm_rec, dim3(256), dim3(256), 0, stream,
                           Gin, Whhf, Whhb, h0, c0, hs, hbuf, cbuf, ctr, t0, CT);
    }
    hipLaunchKernelGGL(logits_k, dim3((BATCH * LSEQ) / 16), dim3(256), 0, stream,
                       hs, Wout, bout, lgts);
    hipLaunchKernelGGL(viterbi_k, dim3(BATCH), dim3(64), 0, stream,
                       lgts, trans, out);
}